// Round 1
// baseline (1115.781 us; speedup 1.0000x reference)
//
#include <hip/hip_runtime.h>
#include <hip/hip_bf16.h>
#include <stdint.h>

typedef _Float16 f16x8 __attribute__((ext_vector_type(8)));
typedef float f32x4 __attribute__((ext_vector_type(4)));
typedef unsigned long long u64;
typedef unsigned int u32;

#define N_CODES 16384
#define N_VEC   16384
#define EMBED   256

// z_q floats, then loss, then indices (as float)
#define OUT_ZQ_ELEMS 4194304
#define OUT_LOSS_OFF 4194304
#define OUT_IDX_OFF  4194305

// ws layout (bytes)
#define WS_EHI   0u
#define WS_ELO   8388608u
#define WS_E2    16777216u
#define WS_PART  16842752u   // u64 [2 splits][16384 rows][2 keys] = 524288 B
#define WS_FKEY  17367040u   // u64 [16384] = 131072 B
#define WS_COUNT 17498112u   // int
#define WS_LIST  17498128u   // int [256]

#define MARGIN 4.0e-3f

// LDS geometry (f16 units). Rows padded so 16B-chunk stride is odd -> even bank spread.
#define A_STRIDE 264   // 256 + 8 pad  (33 chunks, odd)
#define B_STRIDE 40    // 32 + 8 pad   (5 chunks, odd)
#define LDS_AHI 0
#define LDS_ALO (128*A_STRIDE)
#define LDS_BHI (2*128*A_STRIDE)
#define LDS_BLO (2*128*A_STRIDE + 128*B_STRIDE)
#define LDS_RED_BYTES_OFF ((2*128*A_STRIDE + 2*128*B_STRIDE)*2)
#define LDS_TOTAL_BYTES (LDS_RED_BYTES_OFF + 128*2*2*8)   // 159744

__device__ __forceinline__ u32 sortable_from_f32(float f) {
  u32 u = __float_as_uint(f);
  return (u & 0x80000000u) ? ~u : (u | 0x80000000u);
}
__device__ __forceinline__ float f32_from_sortable(u32 s) {
  u32 u = (s & 0x80000000u) ? (s & 0x7FFFFFFFu) : ~s;
  return __uint_as_float(u);
}

// ---------------- prep: embedding -> f16 hi/lo + exact-ish ||e||^2 ----------------
__global__ __launch_bounds__(256) void k_prep(const float* __restrict__ emb,
                                              _Float16* __restrict__ ehi,
                                              _Float16* __restrict__ elo,
                                              float* __restrict__ e2) {
  const int code = blockIdx.x * 4 + (threadIdx.x >> 6);
  const int lane = threadIdx.x & 63;
  const float4 v = ((const float4*)emb)[code * 64 + lane];
  union { _Float16 f[4]; uint2 u2; } ph, pl;
  float vv[4] = {v.x, v.y, v.z, v.w};
  double s = 0.0;
#pragma unroll
  for (int j = 0; j < 4; ++j) {
    _Float16 h = (_Float16)vv[j];
    _Float16 l = (_Float16)(vv[j] - (float)h);
    ph.f[j] = h; pl.f[j] = l;
    s += (double)vv[j] * (double)vv[j];
  }
  ((uint2*)ehi)[code * 64 + lane] = ph.u2;
  ((uint2*)elo)[code * 64 + lane] = pl.u2;
#pragma unroll
  for (int off = 32; off; off >>= 1) s += __shfl_down(s, off);
  if (lane == 0) e2[code] = (float)s;
}

// ---------------- main fused GEMM + top-2 argmin ----------------
// grid 256: blockIdx & 127 = row tile (128 rows), blockIdx >> 7 = code split (8192 codes)
__global__ __launch_bounds__(256, 1) void k_gemm(const float* __restrict__ z,
                                                 const _Float16* __restrict__ ehi,
                                                 const _Float16* __restrict__ elo,
                                                 const float* __restrict__ e2,
                                                 u64* __restrict__ part) {
  extern __shared__ char smem_raw[];
  _Float16* Ahi = (_Float16*)smem_raw;
  _Float16* Alo = Ahi + LDS_ALO;
  _Float16* Bhi = Ahi + LDS_BHI;
  _Float16* Blo = Ahi + LDS_BLO;
  u64* red = (u64*)(smem_raw + LDS_RED_BYTES_OFF);

  const int tid = threadIdx.x;
  const int row_blk = blockIdx.x & 127;
  const int split = blockIdx.x >> 7;
  const int row0 = row_blk * 128;
  const int bb = row0 >> 10;          // batch index (128 rows stay in one b)
  const int hw0 = row0 & 1023;

  // ---- stage A tile (128 rows x 256 dims), fused NCHW transpose + f16 split ----
  {
    const float4* z4 = (const float4*)z;
    const int fq = tid & 31, cg = tid >> 5;
    for (int i = 0; i < 32; ++i) {
      const int c = i * 8 + cg;
      float4 v = z4[(bb * 256 + c) * 256 + (hw0 >> 2) + fq];
      float vv[4] = {v.x, v.y, v.z, v.w};
      const int r = fq * 4;
#pragma unroll
      for (int j = 0; j < 4; ++j) {
        _Float16 h = (_Float16)vv[j];
        _Float16 l = (_Float16)(vv[j] - (float)h);
        Ahi[(r + j) * A_STRIDE + c] = h;
        Alo[(r + j) * A_STRIDE + c] = l;
      }
    }
  }

  const int lane = tid & 63, wv = tid >> 6;
  const int wm = (wv & 1) * 64, wn = (wv >> 1) * 64;
  const int fr = lane & 15, q = lane >> 4;

  f32x4 acc[4][4] = {};
  const f32x4 vzero = {0.0f, 0.0f, 0.0f, 0.0f};
  u64 k1[4][4], k2[4][4];
#pragma unroll
  for (int a = 0; a < 4; ++a)
#pragma unroll
    for (int b2 = 0; b2 < 4; ++b2) { k1[a][b2] = ~0ull; k2[a][b2] = ~0ull; }

  const int code_base0 = split * 8192;

  uint4 ph[2], pl[2];
  auto prefetch = [&](int gs) {
    const int ct = gs >> 3, cs = gs & 7;
#pragma unroll
    for (int u = 0; u < 2; ++u) {
      const int cl = tid + u * 256;          // chunk id within step tile
      const int r = cl >> 2, ch = cl & 3;
      const int gcode = code_base0 + ct * 128 + r;
      const int gidx = (gcode * 256 + cs * 32 + ch * 8) >> 3;   // uint4 index
      ph[u] = ((const uint4*)ehi)[gidx];
      pl[u] = ((const uint4*)elo)[gidx];
    }
  };
  prefetch(0);

  for (int gs = 0; gs < 512; ++gs) {
    const int ct = gs >> 3, cs = gs & 7;
    __syncthreads();
    // commit B tile for this step
#pragma unroll
    for (int u = 0; u < 2; ++u) {
      const int cl = tid + u * 256;
      const int r = cl >> 2, ch = cl & 3;
      *(uint4*)(Bhi + r * B_STRIDE + ch * 8) = ph[u];
      *(uint4*)(Blo + r * B_STRIDE + ch * 8) = pl[u];
    }
    __syncthreads();
    if (gs + 1 < 512) prefetch(gs + 1);

    f16x8 bh[4], bl[4];
#pragma unroll
    for (int nf = 0; nf < 4; ++nf) {
      const int nrow = wn + nf * 16 + fr;
      bh[nf] = *(const f16x8*)(Bhi + nrow * B_STRIDE + q * 8);
      bl[nf] = *(const f16x8*)(Blo + nrow * B_STRIDE + q * 8);
    }
#pragma unroll
    for (int mf = 0; mf < 4; ++mf) {
      const int mrow = wm + mf * 16 + fr;
      f16x8 ah = *(const f16x8*)(Ahi + mrow * A_STRIDE + cs * 32 + q * 8);
      f16x8 al = *(const f16x8*)(Alo + mrow * A_STRIDE + cs * 32 + q * 8);
#pragma unroll
      for (int nf = 0; nf < 4; ++nf) {
        acc[mf][nf] = __builtin_amdgcn_mfma_f32_16x16x32_f16(ah, bh[nf], acc[mf][nf], 0, 0, 0);
        acc[mf][nf] = __builtin_amdgcn_mfma_f32_16x16x32_f16(al, bh[nf], acc[mf][nf], 0, 0, 0);
        acc[mf][nf] = __builtin_amdgcn_mfma_f32_16x16x32_f16(ah, bl[nf], acc[mf][nf], 0, 0, 0);
      }
    }

    if (cs == 7) {
      // epilogue: score = ||e||^2 - 2*dot ; update per-lane top-2 keys
      const int cb = code_base0 + ct * 128;
#pragma unroll
      for (int nf = 0; nf < 4; ++nf) {
        const int gcode = cb + wn + nf * 16 + fr;
        const float ev = e2[gcode];
#pragma unroll
        for (int mf = 0; mf < 4; ++mf) {
#pragma unroll
          for (int rg = 0; rg < 4; ++rg) {
            const float sc = ev - 2.0f * acc[mf][nf][rg];
            const u64 key = ((u64)sortable_from_f32(sc) << 32) | (u32)gcode;
            const u64 old1 = k1[mf][rg];
            const bool lt = key < old1;
            k1[mf][rg] = lt ? key : old1;
            const u64 cand2 = lt ? old1 : key;
            const u64 old2 = k2[mf][rg];
            k2[mf][rg] = cand2 < old2 ? cand2 : old2;
          }
        }
      }
#pragma unroll
      for (int mf = 0; mf < 4; ++mf)
#pragma unroll
        for (int nf = 0; nf < 4; ++nf) acc[mf][nf] = vzero;
    }
  }

  // reduce top-2 across the 16 column-lanes
#pragma unroll
  for (int mf = 0; mf < 4; ++mf) {
#pragma unroll
    for (int rg = 0; rg < 4; ++rg) {
      u64 a1 = k1[mf][rg], a2 = k2[mf][rg];
#pragma unroll
      for (int off = 1; off < 16; off <<= 1) {
        u64 o1 = __shfl_xor(a1, off);
        u64 o2 = __shfl_xor(a2, off);
        u64 n1 = a1 < o1 ? a1 : o1;
        u64 mx = a1 < o1 ? o1 : a1;
        u64 mn2 = a2 < o2 ? a2 : o2;
        a1 = n1;
        a2 = mx < mn2 ? mx : mn2;
      }
      if (fr == 0) {
        const int rloc = wm + mf * 16 + q * 4 + rg;
        red[(rloc * 2 + (wv >> 1)) * 2 + 0] = a1;
        red[(rloc * 2 + (wv >> 1)) * 2 + 1] = a2;
      }
    }
  }
  __syncthreads();
  if (tid < 128) {
    u64 a1 = red[(tid * 2 + 0) * 2 + 0], a2 = red[(tid * 2 + 0) * 2 + 1];
    u64 b1 = red[(tid * 2 + 1) * 2 + 0], b2 = red[(tid * 2 + 1) * 2 + 1];
    u64 m1 = a1 < b1 ? a1 : b1;
    u64 mx = a1 < b1 ? b1 : a1;
    u64 mn2 = a2 < b2 ? a2 : b2;
    u64 m2 = mx < mn2 ? mx : mn2;
    const int grow = row0 + tid;
    part[(split * N_VEC + grow) * 2 + 0] = m1;
    part[(split * N_VEC + grow) * 2 + 1] = m2;
  }
}

// ---------------- merge splits, flag near-ties ----------------
__global__ __launch_bounds__(256) void k_merge(const u64* __restrict__ part,
                                               u64* __restrict__ fkey,
                                               int* __restrict__ count,
                                               int* __restrict__ list) {
  const int r = blockIdx.x * 256 + threadIdx.x;
  u64 a1 = part[r * 2], a2 = part[r * 2 + 1];
  u64 b1 = part[(N_VEC + r) * 2], b2 = part[(N_VEC + r) * 2 + 1];
  u64 m1 = a1 < b1 ? a1 : b1;
  u64 mx = a1 < b1 ? b1 : a1;
  u64 mn2 = a2 < b2 ? a2 : b2;
  u64 m2 = mx < mn2 ? mx : mn2;
  const float s1 = f32_from_sortable((u32)(m1 >> 32));
  const float s2 = f32_from_sortable((u32)(m2 >> 32));
  if (s2 - s1 < MARGIN) {
    const int p = atomicAdd(count, 1);
    if (p < 256) list[p] = r;
    fkey[r] = ~0ull;
  } else {
    fkey[r] = m1;
  }
}

// ---------------- exact fp64 rescue for flagged rows ----------------
// grid 8192: blockIdx>>5 = list slot, blockIdx&31 = code chunk (512 codes)
__global__ __launch_bounds__(256) void k_rescue(const float* __restrict__ z,
                                                const float* __restrict__ emb,
                                                const int* __restrict__ count,
                                                const int* __restrict__ list,
                                                u64* __restrict__ fkey) {
  const int li = blockIdx.x >> 5;
  const int chunk = blockIdx.x & 31;
  int cnt = *count; if (cnt > 256) cnt = 256;
  if (li >= cnt) return;
  const int row = list[li];
  __shared__ float zl[256];
  const int b = row >> 10, hw = row & 1023;
  zl[threadIdx.x] = z[(b * 256 + threadIdx.x) * 1024 + hw];
  __syncthreads();
  const int lane = threadIdx.x & 63, wvi = threadIdx.x >> 6;
  const int c0 = lane * 4;
  const float z0 = zl[c0], z1 = zl[c0 + 1], z2 = zl[c0 + 2], z3 = zl[c0 + 3];
  u64 local = ~0ull;
  for (int it = 0; it < 128; ++it) {
    const int code = chunk * 512 + wvi * 128 + it;
    const float4 e4 = ((const float4*)emb)[code * 64 + lane];
    double dz = (double)e4.x * z0 + (double)e4.y * z1 + (double)e4.z * z2 + (double)e4.w * z3;
    double de = (double)e4.x * e4.x + (double)e4.y * e4.y + (double)e4.z * e4.z + (double)e4.w * e4.w;
#pragma unroll
    for (int off = 32; off; off >>= 1) { dz += __shfl_down(dz, off); de += __shfl_down(de, off); }
    if (lane == 0) {
      const double sc = de - 2.0 * dz;
      long long qv = (long long)((sc + 1024.0) * 8589934592.0);   // 2^33 fixed point
      if (qv < 0) qv = 0;
      const u64 key = ((u64)qv << 14) | (u32)code;
      if (key < local) local = key;
    }
  }
  if (lane == 0) atomicMin(fkey + row, local);
}

// ---------------- output: z_q (straight-through), loss, indices ----------------
__global__ __launch_bounds__(256) void k_out(const float* __restrict__ z,
                                             const float* __restrict__ emb,
                                             const u64* __restrict__ fkey,
                                             float* __restrict__ out) {
  const int gid = blockIdx.x * 256 + threadIdx.x;   // 0..1048575 (float4 units)
  const int f0 = gid * 4;
  const int bc = f0 >> 10;
  const int hw = f0 & 1023;
  const int c = bc & 255, b = bc >> 8;
  const int n = b * 1024 + hw;
  const float4 z4 = ((const float4*)z)[gid];
  float zz[4] = {z4.x, z4.y, z4.z, z4.w};
  float o[4];
#pragma unroll
  for (int j = 0; j < 4; ++j) {
    const int idx = (int)(fkey[n + j] & 0x3FFFull);
    const float ev = emb[idx * 256 + c];
    o[j] = zz[j] + (ev - zz[j]);
  }
  float4 ov = {o[0], o[1], o[2], o[3]};
  ((float4*)out)[gid] = ov;
  if (gid == 0) out[OUT_LOSS_OFF] = 0.0f;
  if (gid < N_VEC) out[OUT_IDX_OFF + gid] = (float)(u32)(fkey[gid] & 0x3FFFull);
}

extern "C" void kernel_launch(void* const* d_in, const int* in_sizes, int n_in,
                              void* d_out, int out_size, void* d_ws, size_t ws_size,
                              hipStream_t stream) {
  const float* z = (const float*)d_in[0];
  const float* emb = (const float*)d_in[1];
  float* out = (float*)d_out;
  char* ws = (char*)d_ws;

  _Float16* ehi = (_Float16*)(ws + WS_EHI);
  _Float16* elo = (_Float16*)(ws + WS_ELO);
  float* e2 = (float*)(ws + WS_E2);
  u64* part = (u64*)(ws + WS_PART);
  u64* fkey = (u64*)(ws + WS_FKEY);
  int* count = (int*)(ws + WS_COUNT);
  int* list = (int*)(ws + WS_LIST);

  hipFuncSetAttribute((const void*)k_gemm, hipFuncAttributeMaxDynamicSharedMemorySize,
                      LDS_TOTAL_BYTES);
  hipMemsetAsync(ws + WS_COUNT, 0, 4, stream);

  k_prep<<<4096, 256, 0, stream>>>(emb, ehi, elo, e2);
  k_gemm<<<256, 256, LDS_TOTAL_BYTES, stream>>>(z, ehi, elo, e2, part);
  k_merge<<<64, 256, 0, stream>>>(part, fkey, count, list);
  k_rescue<<<8192, 256, 0, stream>>>(z, emb, count, list, fkey);
  k_out<<<4096, 256, 0, stream>>>(z, emb, fkey, out);
}